// Round 15
// baseline (250.196 us; speedup 1.0000x reference)
//
#include <hip/hip_runtime.h>

#define NN 50000
#define NE 800000
#define IND 768
#define CH  128    // output channels per node for both layers
#define NBLK 196   // ceil(NN/256)
#define GBM 64
#define MBLKS 782  // ceil(NN/GBM)

typedef __attribute__((ext_vector_type(8))) short bf16x8;
typedef __attribute__((ext_vector_type(4))) float f32x4;

// ---------------- bf16 split helpers ----------------
__device__ __forceinline__ unsigned short bf16_rne(float f) {
    unsigned u = __float_as_uint(f);
    u += 0x7fffu + ((u >> 16) & 1u);
    return (unsigned short)(u >> 16);
}
__device__ __forceinline__ float bf16_to_f(unsigned short b) {
    return __uint_as_float(((unsigned)b) << 16);
}

// fast split via packed cvt: hi = cvt_pk(v), lo = cvt_pk(v - hi)
__device__ __forceinline__ void cvt_split_pk(const float4& u0, const float4& u1,
                                             uint4& hi, uint4& lo)
{
    unsigned h0, h1, h2, h3;
    asm("v_cvt_pk_bf16_f32 %0, %1, %2" : "=v"(h0) : "v"(u0.x), "v"(u0.y));
    asm("v_cvt_pk_bf16_f32 %0, %1, %2" : "=v"(h1) : "v"(u0.z), "v"(u0.w));
    asm("v_cvt_pk_bf16_f32 %0, %1, %2" : "=v"(h2) : "v"(u1.x), "v"(u1.y));
    asm("v_cvt_pk_bf16_f32 %0, %1, %2" : "=v"(h3) : "v"(u1.z), "v"(u1.w));
    const float l0 = u0.x - __uint_as_float(h0 << 16);
    const float l1 = u0.y - __uint_as_float(h0 & 0xffff0000u);
    const float l2 = u0.z - __uint_as_float(h1 << 16);
    const float l3 = u0.w - __uint_as_float(h1 & 0xffff0000u);
    const float l4 = u1.x - __uint_as_float(h2 << 16);
    const float l5 = u1.y - __uint_as_float(h2 & 0xffff0000u);
    const float l6 = u1.z - __uint_as_float(h3 << 16);
    const float l7 = u1.w - __uint_as_float(h3 & 0xffff0000u);
    unsigned g0, g1, g2, g3;
    asm("v_cvt_pk_bf16_f32 %0, %1, %2" : "=v"(g0) : "v"(l0), "v"(l1));
    asm("v_cvt_pk_bf16_f32 %0, %1, %2" : "=v"(g1) : "v"(l2), "v"(l3));
    asm("v_cvt_pk_bf16_f32 %0, %1, %2" : "=v"(g2) : "v"(l4), "v"(l5));
    asm("v_cvt_pk_bf16_f32 %0, %1, %2" : "=v"(g3) : "v"(l6), "v"(l7));
    hi = make_uint4(h0, h1, h2, h3);
    lo = make_uint4(g0, g1, g2, g3);
}

// ---------------- prep: W -> K-tiled (32-k), 8-way-swizzled bf16 hi/lo planes ----------------
__global__ void prep_b1(const float* __restrict__ W1,
                        unsigned short* __restrict__ Bhi, unsigned short* __restrict__ Blo)
{
    int idx = blockIdx.x * blockDim.x + threadIdx.x;   // n*IND + k
    if (idx >= CH * IND) return;
    int n = idx / IND, k = idx % IND;
    float v = W1[(size_t)(n >> 5) * IND * 32 + (size_t)k * 32 + (n & 31)];
    int kt = k >> 5, kk = k & 31, j = kk >> 3, e = kk & 7;
    int g = n * 4 + (j ^ ((n >> 1) & 3));
    int off = kt * 4096 + g * 8 + e;
    unsigned short hi = bf16_rne(v);
    float lo = v - bf16_to_f(hi);
    Bhi[off] = hi;
    Blo[off] = bf16_rne(lo);
}

__global__ void prep_b2(const float* __restrict__ W2,
                        unsigned short* __restrict__ Bhi, unsigned short* __restrict__ Blo)
{
    int idx = blockIdx.x * blockDim.x + threadIdx.x;   // n*CH + k
    if (idx >= CH * CH) return;
    int n = idx / CH, k = idx % CH;
    float v = W2[(size_t)k * CH + n];
    int kt = k >> 5, kk = k & 31, j = kk >> 3, e = kk & 7;
    int g = n * 4 + (j ^ ((n >> 1) & 3));
    int off = kt * 4096 + g * 8 + e;
    unsigned short hi = bf16_rne(v);
    float lo = v - bf16_to_f(hi);
    Bhi[off] = hi;
    Blo[off] = bf16_rne(lo);
}

// ---------------- GEMM with fused epilogue: z16 + s_src/s_dst. GBK=64 (2 subtiles/iter) ----------------
template<int H>
__global__ __launch_bounds__(256) void gemm_fused(
    const float* __restrict__ A,
    const unsigned short* __restrict__ Bthi, const unsigned short* __restrict__ Btlo,
    const float* __restrict__ av,            // attention vec: [H][2*(128/H)]
    unsigned short* __restrict__ Z16,
    float* __restrict__ ss, float* __restrict__ sd, int K)
{
    __shared__ unsigned short Ahi[2][2048];    // [sub][64 rows x 4 gran x 8]
    __shared__ unsigned short Alo[2][2048];
    __shared__ unsigned short Bs[2][2][4096];  // [sub][plane][4096]
    __shared__ float sred[2][64][2];           // H==1 cross-wave reduce

    const int t = threadIdx.x;
    const int lane = t & 63;
    const int w = t >> 6;
    const int wr = w >> 1, wc = w & 1;
    const int lrow = lane & 15, kg = lane >> 4;
    const int m0 = blockIdx.x * GBM;
    const int nt = K >> 6;                     // 64-k iterations: 12 (L1), 2 (L2)

    const int ar = t >> 2, aj = t & 3;
    const bool avalid = (m0 + ar) < NN;
    const float* aptr = A + (size_t)(avalid ? (m0 + ar) : 0) * K + aj * 8;
    const int ag8 = (ar * 4 + (aj ^ ((ar >> 1) & 3))) * 8;

    int aoff[2];
    #pragma unroll
    for (int mi = 0; mi < 2; ++mi) {
        const int r = wr * 32 + mi * 16 + lrow;
        aoff[mi] = (r * 4 + (kg ^ ((r >> 1) & 3))) * 8;
    }
    int boff[4];
    #pragma unroll
    for (int ni = 0; ni < 4; ++ni) {
        const int n = wc * 64 + ni * 16 + lrow;
        boff[ni] = (n * 4 + (kg ^ ((n >> 1) & 3))) * 8;
    }

    f32x4 acc[2][4];
    #pragma unroll
    for (int i = 0; i < 2; ++i)
        #pragma unroll
        for (int j = 0; j < 4; ++j) acc[i][j] = (f32x4)(0.f);

    for (int kt = 0; kt < nt; ++kt) {
        // ---- A: load 64 k (two 32-k subtiles) as raw fp32 ----
        float4 v00 = make_float4(0.f, 0.f, 0.f, 0.f), v01 = v00, v10 = v00, v11 = v00;
        if (avalid) {
            const float* p = aptr + kt * 64;
            v00 = *(const float4*)p;        v01 = *(const float4*)(p + 4);
            v10 = *(const float4*)(p + 32); v11 = *(const float4*)(p + 36);
        }
        __syncthreads();                    // previous iteration's LDS reads done
        {
            uint4 hi, lo;
            cvt_split_pk(v00, v01, hi, lo);
            *(uint4*)&Ahi[0][ag8] = hi;
            *(uint4*)&Alo[0][ag8] = lo;
            cvt_split_pk(v10, v11, hi, lo);
            *(uint4*)&Ahi[1][ag8] = hi;
            *(uint4*)&Alo[1][ag8] = lo;
        }
        // ---- B: 2 subtiles x 16 async 1KB DMA chunks ----
        #pragma unroll
        for (int sub = 0; sub < 2; ++sub) {
            #pragma unroll
            for (int i = 0; i < 4; ++i) {
                const int c = w * 4 + i;
                const int plane = c >> 3;
                const int co = (c & 7) * 512;
                const unsigned short* gs =
                    (plane ? Btlo : Bthi) + (size_t)(kt * 2 + sub) * 4096 + co + lane * 8;
                __builtin_amdgcn_global_load_lds(
                    (const __attribute__((address_space(1))) unsigned int*)gs,
                    (__attribute__((address_space(3))) unsigned int*)&Bs[sub][plane][co],
                    16, 0, 0);
            }
        }
        __syncthreads();                    // drains DMA (vmcnt) + A stores (lgkm)

        // ---- 2 subtiles x 24 MFMA ----
        #pragma unroll
        for (int sub = 0; sub < 2; ++sub) {
            bf16x8 ahi[2], alo[2];
            #pragma unroll
            for (int mi = 0; mi < 2; ++mi) {
                ahi[mi] = *(const bf16x8*)&Ahi[sub][aoff[mi]];
                alo[mi] = *(const bf16x8*)&Alo[sub][aoff[mi]];
            }
            #pragma unroll
            for (int ni = 0; ni < 4; ++ni) {
                const bf16x8 bhi = *(const bf16x8*)&Bs[sub][0][boff[ni]];
                const bf16x8 blo = *(const bf16x8*)&Bs[sub][1][boff[ni]];
                #pragma unroll
                for (int mi = 0; mi < 2; ++mi) {
                    acc[mi][ni] = __builtin_amdgcn_mfma_f32_16x16x32_bf16(ahi[mi], bhi, acc[mi][ni], 0, 0, 0);
                    acc[mi][ni] = __builtin_amdgcn_mfma_f32_16x16x32_bf16(ahi[mi], blo, acc[mi][ni], 0, 0, 0);
                    acc[mi][ni] = __builtin_amdgcn_mfma_f32_16x16x32_bf16(alo[mi], bhi, acc[mi][ni], 0, 0, 0);
                }
            }
        }
    }

    // ---- epilogue: z16 store + per-head score dots ----
    const int NH = (H == 4) ? 2 : 1;
    float asc[4], adc[4];
    #pragma unroll
    for (int ni = 0; ni < 4; ++ni) {
        const int col = wc * 64 + ni * 16 + lrow;
        if (H == 4) {
            const int hh = col >> 5, d = col & 31;
            asc[ni] = av[hh * 64 + d];
            adc[ni] = av[hh * 64 + 32 + d];
        } else {
            asc[ni] = av[col];
            adc[ni] = av[128 + col];
        }
    }
    float es[2][4][2], ed[2][4][2];
    #pragma unroll
    for (int mi = 0; mi < 2; ++mi)
        #pragma unroll
        for (int j = 0; j < 4; ++j)
            #pragma unroll
            for (int q = 0; q < 2; ++q) { es[mi][j][q] = 0.f; ed[mi][j][q] = 0.f; }

    #pragma unroll
    for (int mi = 0; mi < 2; ++mi) {
        #pragma unroll
        for (int ni = 0; ni < 4; ++ni) {
            const int hh = (H == 4) ? (ni >> 1) : 0;
            const f32x4 a = acc[mi][ni];
            #pragma unroll
            for (int j = 0; j < 4; ++j) {
                es[mi][j][hh] = fmaf(a[j], asc[ni], es[mi][j][hh]);
                ed[mi][j][hh] = fmaf(a[j], adc[ni], ed[mi][j][hh]);
            }
        }
    }
    #pragma unroll
    for (int mi = 0; mi < 2; ++mi) {
        const int rbase = m0 + wr * 32 + mi * 16 + kg * 4;
        #pragma unroll
        for (int ni = 0; ni < 4; ++ni) {
            const int col = wc * 64 + ni * 16 + lrow;
            const f32x4 a = acc[mi][ni];
            #pragma unroll
            for (int j = 0; j < 4; ++j) {
                const int r = rbase + j;
                if (r < NN) Z16[(size_t)r * CH + col] = bf16_rne(a[j]);
            }
        }
    }
    #pragma unroll
    for (int off = 1; off < 16; off <<= 1) {
        #pragma unroll
        for (int mi = 0; mi < 2; ++mi)
            #pragma unroll
            for (int j = 0; j < 4; ++j)
                #pragma unroll
                for (int q = 0; q < NH; ++q) {
                    es[mi][j][q] += __shfl_xor(es[mi][j][q], off, 64);
                    ed[mi][j][q] += __shfl_xor(ed[mi][j][q], off, 64);
                }
    }
    if (H == 4) {
        if (lrow == 0) {
            #pragma unroll
            for (int mi = 0; mi < 2; ++mi)
                #pragma unroll
                for (int j = 0; j < 4; ++j) {
                    const int r = m0 + wr * 32 + mi * 16 + kg * 4 + j;
                    if (r < NN) {
                        #pragma unroll
                        for (int q = 0; q < 2; ++q) {
                            ss[r * 4 + wc * 2 + q] = es[mi][j][q];
                            sd[r * 4 + wc * 2 + q] = ed[mi][j][q];
                        }
                    }
                }
        }
    } else {
        if (lrow == 0) {
            #pragma unroll
            for (int mi = 0; mi < 2; ++mi)
                #pragma unroll
                for (int j = 0; j < 4; ++j) {
                    const int rl = wr * 32 + mi * 16 + kg * 4 + j;
                    sred[0][rl][wc] = es[mi][j][0];
                    sred[1][rl][wc] = ed[mi][j][0];
                }
        }
        __syncthreads();
        if (t < 64) {
            const int r = m0 + t;
            if (r < NN) {
                ss[r] = sred[0][t][0] + sred[0][t][1];
                sd[r] = sred[1][t][0] + sred[1][t][1];
            }
        }
    }
}

// ---------------- CSR build ----------------
__global__ __launch_bounds__(256) void zero_cc(int* __restrict__ counts, int* __restrict__ cursor)
{
    int i = blockIdx.x * 256 + threadIdx.x;
    if (i < NN) { counts[i] = 0; cursor[i] = 0; }
}

__global__ void count_k(const int* __restrict__ dst, int* __restrict__ counts)
{
    int e = blockIdx.x * blockDim.x + threadIdx.x;
    if (e < NE) atomicAdd(&counts[dst[e]], 1);
}

__global__ __launch_bounds__(256) void scan1(const int* __restrict__ counts,
                                             int* __restrict__ exc, int* __restrict__ bsum)
{
    __shared__ int s[256];
    const int t = threadIdx.x;
    const int i = blockIdx.x * 256 + t;
    const int val = (i < NN) ? counts[i] : 0;
    s[t] = val;
    __syncthreads();
    #pragma unroll
    for (int off = 1; off < 256; off <<= 1) {
        int v = (t >= off) ? s[t - off] : 0;
        __syncthreads();
        s[t] += v;
        __syncthreads();
    }
    if (i < NN) exc[i] = s[t] - val;
    if (t == 255) bsum[blockIdx.x] = s[255];
}

__global__ __launch_bounds__(256) void scan2(const int* __restrict__ bsum,
                                             int* __restrict__ bexc)
{
    __shared__ int s[256];
    const int t = threadIdx.x;
    const int val = (t < NBLK) ? bsum[t] : 0;
    s[t] = val;
    __syncthreads();
    #pragma unroll
    for (int off = 1; off < 256; off <<= 1) {
        int v = (t >= off) ? s[t - off] : 0;
        __syncthreads();
        s[t] += v;
        __syncthreads();
    }
    bexc[t] = s[t] - val;
}

__global__ __launch_bounds__(256) void scan3(const int* __restrict__ exc,
                                             const int* __restrict__ bexc,
                                             int* __restrict__ offsets)
{
    const int i = blockIdx.x * 256 + threadIdx.x;
    if (i < NN) offsets[i] = exc[i] + bexc[i >> 8];
    if (i == 0) offsets[NN] = NE;
}

__global__ void scatter_es(const int* __restrict__ src, const int* __restrict__ dst,
                           const int* __restrict__ offsets, int* __restrict__ cursor,
                           int* __restrict__ es)
{
    int e = blockIdx.x * blockDim.x + threadIdx.x;
    if (e >= NE) return;
    int d = dst[e];
    int p = offsets[d] + atomicAdd(&cursor[d], 1);
    es[p] = src[e];
}

// ---------------- fused softmax + aggregation: one WAVE per dst node, ZERO barriers ----------------
// All LDS slices are wave-private ([wid]); same-wave LDS deps are compiler-handled (lgkmcnt),
// so no __syncthreads anywhere and path choice is per-wave.
template<int H, bool ELU>
__global__ __launch_bounds__(256) void fused_agg(
    const int* __restrict__ offsets, const int* __restrict__ es,
    const float* __restrict__ s_src, const float* __restrict__ s_dst,
    const unsigned short* __restrict__ z16, float* __restrict__ out)
{
    const int wid = threadIdx.x >> 6;
    const int lane = threadIdx.x & 63;
    const int n = blockIdx.x * 4 + wid;     // NN % 4 == 0
    const int beg = offsets[n], end = offsets[n + 1];
    const int deg = end - beg;

    __shared__ float alpha_sh[4][128][H];
    __shared__ int   es_sh[4][128];

    float sdv[H];
    #pragma unroll
    for (int h = 0; h < H; ++h) sdv[h] = s_dst[(size_t)n * H + h];

    const int myh = (H == 4) ? (lane >> 4) : 0;
    float m[H], ssum[H], inv[H];
    #pragma unroll
    for (int h = 0; h < H; ++h) { m[h] = -INFINITY; ssum[h] = 0.f; }
    float2 acc = make_float2(0.f, 0.f);

    if (deg <= 128) {
        // ---- pass 1: gather scores once, cache v in wave-private LDS ----
        for (int idx = lane; idx < deg; idx += 64) {
            const int s = es[beg + idx];
            es_sh[wid][idx] = s;
            if (H == 4) {
                const float4 sv = *(const float4*)&s_src[(size_t)s * 4];
                const float svv[4] = {sv.x, sv.y, sv.z, sv.w};
                float v4[4];
                #pragma unroll
                for (int h = 0; h < 4; ++h) {
                    float v = svv[h] + sdv[h];
                    v = v > 0.f ? v : 0.01f * v;
                    v4[h] = v;
                    const float mn = fmaxf(m[h], v);
                    ssum[h] = ssum[h] * __expf(m[h] - mn) + __expf(v - mn);
                    m[h] = mn;
                }
                *(float4*)&alpha_sh[wid][idx][0] = make_float4(v4[0], v4[1], v4[2], v4[3]);
            } else {
                float v = s_src[s] + sdv[0];
                v = v > 0.f ? v : 0.01f * v;
                alpha_sh[wid][idx][0] = v;
                const float mn = fmaxf(m[0], v);
                ssum[0] = ssum[0] * __expf(m[0] - mn) + __expf(v - mn);
                m[0] = mn;
            }
        }
        // ---- wave reduce: global max, scaled sum ----
        #pragma unroll
        for (int h = 0; h < H; ++h) {
            float mg = m[h];
            #pragma unroll
            for (int off = 1; off < 64; off <<= 1)
                mg = fmaxf(mg, __shfl_xor(mg, off, 64));
            float sg = ssum[h] * __expf(m[h] - mg);
            #pragma unroll
            for (int off = 1; off < 64; off <<= 1)
                sg += __shfl_xor(sg, off, 64);
            m[h] = mg;
            inv[h] = 1.0f / fmaxf(sg, 1e-9f);
        }
        // ---- convert cached v -> alpha in place ----
        for (int idx = lane; idx < deg; idx += 64) {
            #pragma unroll
            for (int h = 0; h < H; ++h)
                alpha_sh[wid][idx][h] = __expf(alpha_sh[wid][idx][h] - m[h]) * inv[h];
        }
        // ---- PV gather, 4-unrolled ----
        int j = 0;
        for (; j + 4 <= deg; j += 4) {
            const int s0 = es_sh[wid][j],     s1 = es_sh[wid][j + 1];
            const int s2 = es_sh[wid][j + 2], s3 = es_sh[wid][j + 3];
            const float a0 = alpha_sh[wid][j][myh],     a1 = alpha_sh[wid][j + 1][myh];
            const float a2 = alpha_sh[wid][j + 2][myh], a3 = alpha_sh[wid][j + 3][myh];
            const ushort2 u0 = *(const ushort2*)&z16[(size_t)s0 * CH + lane * 2];
            const ushort2 u1 = *(const ushort2*)&z16[(size_t)s1 * CH + lane * 2];
            const ushort2 u2 = *(const ushort2*)&z16[(size_t)s2 * CH + lane * 2];
            const ushort2 u3 = *(const ushort2*)&z16[(size_t)s3 * CH + lane * 2];
            acc.x = fmaf(a0, bf16_to_f(u0.x), acc.x); acc.y = fmaf(a0, bf16_to_f(u0.y), acc.y);
            acc.x = fmaf(a1, bf16_to_f(u1.x), acc.x); acc.y = fmaf(a1, bf16_to_f(u1.y), acc.y);
            acc.x = fmaf(a2, bf16_to_f(u2.x), acc.x); acc.y = fmaf(a2, bf16_to_f(u2.y), acc.y);
            acc.x = fmaf(a3, bf16_to_f(u3.x), acc.x); acc.y = fmaf(a3, bf16_to_f(u3.y), acc.y);
        }
        for (; j < deg; ++j) {
            const int s0 = es_sh[wid][j];
            const float a0 = alpha_sh[wid][j][myh];
            const ushort2 u0 = *(const ushort2*)&z16[(size_t)s0 * CH + lane * 2];
            acc.x = fmaf(a0, bf16_to_f(u0.x), acc.x); acc.y = fmaf(a0, bf16_to_f(u0.y), acc.y);
        }
    } else {
        // ---- fallback: chunked, still barrier-free (wave-private LDS) ----
        for (int i = beg + lane; i < end; i += 64) {
            const int s = es[i];
            if (H == 4) {
                const float4 sv = *(const float4*)&s_src[(size_t)s * 4];
                const float svv[4] = {sv.x, sv.y, sv.z, sv.w};
                #pragma unroll
                for (int h = 0; h < 4; ++h) {
                    float v = svv[h] + sdv[h];
                    v = v > 0.f ? v : 0.01f * v;
                    const float mn = fmaxf(m[h], v);
                    ssum[h] = ssum[h] * __expf(m[h] - mn) + __expf(v - mn);
                    m[h] = mn;
                }
            } else {
                float v = s_src[s] + sdv[0];
                v = v > 0.f ? v : 0.01f * v;
                const float mn = fmaxf(m[0], v);
                ssum[0] = ssum[0] * __expf(m[0] - mn) + __expf(v - mn);
                m[0] = mn;
            }
        }
        #pragma unroll
        for (int h = 0; h < H; ++h) {
            float mg = m[h];
            #pragma unroll
            for (int off = 1; off < 64; off <<= 1)
                mg = fmaxf(mg, __shfl_xor(mg, off, 64));
            float sg = ssum[h] * __expf(m[h] - mg);
            #pragma unroll
            for (int off = 1; off < 64; off <<= 1)
                sg += __shfl_xor(sg, off, 64);
            m[h] = mg;
            inv[h] = 1.0f / fmaxf(sg, 1e-9f);
        }
        const int nch = (deg + 127) >> 7;
        for (int k = 0; k < nch; ++k) {
            const int base = beg + k * 128;
            int cnt = end - base;
            cnt = cnt < 0 ? 0 : (cnt > 128 ? 128 : cnt);
            for (int idx = lane; idx < cnt; idx += 64) {
                const int s = es[base + idx];
                es_sh[wid][idx] = s;
                if (H == 4) {
                    const float4 sv = *(const float4*)&s_src[(size_t)s * 4];
                    const float svv[4] = {sv.x, sv.y, sv.z, sv.w};
                    float a4[4];
                    #pragma unroll
                    for (int h = 0; h < 4; ++h) {
                        float v = svv[h] + sdv[h];
                        v = v > 0.f ? v : 0.01f * v;
                        a4[h] = __expf(v - m[h]) * inv[h];
                    }
                    *(float4*)&alpha_sh[wid][idx][0] = make_float4(a4[0], a4[1], a4[2], a4[3]);
                } else {
                    float v = s_src[s] + sdv[0];
                    v = v > 0.f ? v : 0.01f * v;
                    alpha_sh[wid][idx][0] = __expf(v - m[0]) * inv[0];
                }
            }
            for (int j = 0; j < cnt; ++j) {
                const int s0 = es_sh[wid][j];
                const float a0 = alpha_sh[wid][j][myh];
                const ushort2 u0 = *(const ushort2*)&z16[(size_t)s0 * CH + lane * 2];
                acc.x = fmaf(a0, bf16_to_f(u0.x), acc.x);
                acc.y = fmaf(a0, bf16_to_f(u0.y), acc.y);
            }
        }
    }

    if (ELU) {
        acc.x = acc.x > 0.f ? acc.x : expm1f(acc.x);
        acc.y = acc.y > 0.f ? acc.y : expm1f(acc.y);
    }
    *(float2*)&out[(size_t)n * CH + lane * 2] = acc;
}

// ---------------- host ----------------
extern "C" void kernel_launch(void* const* d_in, const int* in_sizes, int n_in,
                              void* d_out, int out_size, void* d_ws, size_t ws_size,
                              hipStream_t stream)
{
    const float* h   = (const float*)d_in[0];
    const float* W1  = (const float*)d_in[1];
    const float* a1  = (const float*)d_in[2];
    const float* W2  = (const float*)d_in[3];
    const float* a2  = (const float*)d_in[4];
    const int*   src = (const int*)d_in[5];
    const int*   dst = (const int*)d_in[6];
    float* out = (float*)d_out;

    char* ws = (char*)d_ws;
    unsigned short* Bthi1 = (unsigned short*)(ws + 0);          // 192KB
    unsigned short* Btlo1 = (unsigned short*)(ws + 196608);     // 192KB
    unsigned short* Bthi2 = (unsigned short*)(ws + 393216);     // 32KB
    unsigned short* Btlo2 = (unsigned short*)(ws + 425984);     // 32KB
    float* ss      = (float*)(ws + 458752);                     // 800KB
    float* sd      = (float*)(ws + 1258752);                    // 800KB
    int*   counts  = (int*)  (ws + 2058752);                    // 200KB
    int*   exc     = (int*)  (ws + 2258752);                    // 200KB
    int*   bsum    = (int*)  (ws + 2458752);                    // 1KB
    int*   bexc    = (int*)  (ws + 2459776);                    // 1KB
    int*   offsets = (int*)  (ws + 2460800);                    // 200KB+4
    int*   cursor  = (int*)  (ws + 2661056);                    // 200KB
    int*   es      = (int*)  (ws + 2861056);                    // 3.2MB
    unsigned short* z16 = (unsigned short*)(ws + 6061056);      // 12.8MB
    float* h1      = (float*)(ws + 18861056);                   // 25.6MB

    const int EB = 256;
    const int egrid = (NE + EB - 1) / EB;
    const int sgrid = NN / 4;

    // --- CSR build (shared by both layers) ---
    zero_cc<<<NBLK, 256, 0, stream>>>(counts, cursor);
    count_k<<<egrid, EB, 0, stream>>>(dst, counts);
    scan1<<<NBLK, 256, 0, stream>>>(counts, exc, bsum);
    scan2<<<1, 256, 0, stream>>>(bsum, bexc);
    scan3<<<NBLK, 256, 0, stream>>>(exc, bexc, offsets);
    scatter_es<<<egrid, EB, 0, stream>>>(src, dst, offsets, cursor, es);

    // --- weight prep (split bf16, tiled+swizzled) ---
    prep_b1<<<(CH * IND + 255) / 256, 256, 0, stream>>>(W1, Bthi1, Btlo1);
    prep_b2<<<(CH * CH + 255) / 256, 256, 0, stream>>>(W2, Bthi2, Btlo2);

    // --- layer 1: GEMM (fused z16 + scores) -> aggregate ---
    gemm_fused<4><<<MBLKS, 256, 0, stream>>>(h, Bthi1, Btlo1, a1, z16, ss, sd, IND);
    fused_agg<4, true><<<sgrid, 256, 0, stream>>>(offsets, es, ss, sd, z16, h1);

    // --- layer 2: GEMM (fused z16 + scores) -> aggregate ---
    gemm_fused<1><<<MBLKS, 256, 0, stream>>>(h1, Bthi2, Btlo2, a2, z16, ss, sd, CH);
    fused_agg<1, false><<<sgrid, 256, 0, stream>>>(offsets, es, ss, sd, z16, out);
}

// Round 16
// 240.447 us; speedup vs baseline: 1.0405x; 1.0405x over previous
//
#include <hip/hip_runtime.h>

#define NN 50000
#define NE 800000
#define IND 768
#define CH  128    // output channels per node for both layers
#define NBLK 196   // ceil(NN/256)
#define GBM 64
#define GBK 32
#define MBLKS 782  // ceil(NN/GBM)

typedef __attribute__((ext_vector_type(8))) short bf16x8;
typedef __attribute__((ext_vector_type(4))) float f32x4;

// ---------------- bf16 split helpers ----------------
__device__ __forceinline__ unsigned short bf16_rne(float f) {
    unsigned u = __float_as_uint(f);
    u += 0x7fffu + ((u >> 16) & 1u);
    return (unsigned short)(u >> 16);
}
__device__ __forceinline__ float bf16_to_f(unsigned short b) {
    return __uint_as_float(((unsigned)b) << 16);
}

// fast split via packed cvt: hi = cvt_pk(v), lo = cvt_pk(v - hi)
__device__ __forceinline__ void cvt_split_pk(const float4& u0, const float4& u1,
                                             uint4& hi, uint4& lo)
{
    unsigned h0, h1, h2, h3;
    asm("v_cvt_pk_bf16_f32 %0, %1, %2" : "=v"(h0) : "v"(u0.x), "v"(u0.y));
    asm("v_cvt_pk_bf16_f32 %0, %1, %2" : "=v"(h1) : "v"(u0.z), "v"(u0.w));
    asm("v_cvt_pk_bf16_f32 %0, %1, %2" : "=v"(h2) : "v"(u1.x), "v"(u1.y));
    asm("v_cvt_pk_bf16_f32 %0, %1, %2" : "=v"(h3) : "v"(u1.z), "v"(u1.w));
    const float l0 = u0.x - __uint_as_float(h0 << 16);
    const float l1 = u0.y - __uint_as_float(h0 & 0xffff0000u);
    const float l2 = u0.z - __uint_as_float(h1 << 16);
    const float l3 = u0.w - __uint_as_float(h1 & 0xffff0000u);
    const float l4 = u1.x - __uint_as_float(h2 << 16);
    const float l5 = u1.y - __uint_as_float(h2 & 0xffff0000u);
    const float l6 = u1.z - __uint_as_float(h3 << 16);
    const float l7 = u1.w - __uint_as_float(h3 & 0xffff0000u);
    unsigned g0, g1, g2, g3;
    asm("v_cvt_pk_bf16_f32 %0, %1, %2" : "=v"(g0) : "v"(l0), "v"(l1));
    asm("v_cvt_pk_bf16_f32 %0, %1, %2" : "=v"(g1) : "v"(l2), "v"(l3));
    asm("v_cvt_pk_bf16_f32 %0, %1, %2" : "=v"(g2) : "v"(l4), "v"(l5));
    asm("v_cvt_pk_bf16_f32 %0, %1, %2" : "=v"(g3) : "v"(l6), "v"(l7));
    hi = make_uint4(h0, h1, h2, h3);
    lo = make_uint4(g0, g1, g2, g3);
}

// ---------------- prep: W -> K-tiled, 8-way-swizzled bf16 hi/lo planes ----------------
__global__ void prep_b1(const float* __restrict__ W1,
                        unsigned short* __restrict__ Bhi, unsigned short* __restrict__ Blo)
{
    int idx = blockIdx.x * blockDim.x + threadIdx.x;   // n*IND + k
    if (idx >= CH * IND) return;
    int n = idx / IND, k = idx % IND;
    float v = W1[(size_t)(n >> 5) * IND * 32 + (size_t)k * 32 + (n & 31)];
    int kt = k >> 5, kk = k & 31, j = kk >> 3, e = kk & 7;
    int g = n * 4 + (j ^ ((n >> 1) & 3));
    int off = kt * 4096 + g * 8 + e;
    unsigned short hi = bf16_rne(v);
    float lo = v - bf16_to_f(hi);
    Bhi[off] = hi;
    Blo[off] = bf16_rne(lo);
}

__global__ void prep_b2(const float* __restrict__ W2,
                        unsigned short* __restrict__ Bhi, unsigned short* __restrict__ Blo)
{
    int idx = blockIdx.x * blockDim.x + threadIdx.x;   // n*CH + k
    if (idx >= CH * CH) return;
    int n = idx / CH, k = idx % CH;
    float v = W2[(size_t)k * CH + n];
    int kt = k >> 5, kk = k & 31, j = kk >> 3, e = kk & 7;
    int g = n * 4 + (j ^ ((n >> 1) & 3));
    int off = kt * 4096 + g * 8 + e;
    unsigned short hi = bf16_rne(v);
    float lo = v - bf16_to_f(hi);
    Bhi[off] = hi;
    Blo[off] = bf16_rne(lo);
}

// ---------------- GEMM with fused epilogue: z16 + s_src/s_dst (round-14 schedule) ----------------
template<int H>
__global__ __launch_bounds__(256) void gemm_fused(
    const float* __restrict__ A,
    const unsigned short* __restrict__ Bthi, const unsigned short* __restrict__ Btlo,
    const float* __restrict__ av,            // attention vec: [H][2*(128/H)]
    unsigned short* __restrict__ Z16,
    float* __restrict__ ss, float* __restrict__ sd, int K)
{
    __shared__ unsigned short Ahi[2048];
    __shared__ unsigned short Alo[2048];
    __shared__ unsigned short Bs[2][4096];
    __shared__ float sred[2][64][2];         // H==1 cross-wave reduce

    const int t = threadIdx.x;
    const int lane = t & 63;
    const int w = t >> 6;
    const int wr = w >> 1, wc = w & 1;
    const int lrow = lane & 15, kg = lane >> 4;
    const int m0 = blockIdx.x * GBM;
    const int nt = K >> 5;

    const int ar = t >> 2, aj = t & 3;
    const bool avalid = (m0 + ar) < NN;
    const float* aptr = A + (size_t)(avalid ? (m0 + ar) : 0) * K + aj * 8;
    const int ag8 = (ar * 4 + (aj ^ ((ar >> 1) & 3))) * 8;

    int aoff[2];
    #pragma unroll
    for (int mi = 0; mi < 2; ++mi) {
        const int r = wr * 32 + mi * 16 + lrow;
        aoff[mi] = (r * 4 + (kg ^ ((r >> 1) & 3))) * 8;
    }
    int boff[4];
    #pragma unroll
    for (int ni = 0; ni < 4; ++ni) {
        const int n = wc * 64 + ni * 16 + lrow;
        boff[ni] = (n * 4 + (kg ^ ((n >> 1) & 3))) * 8;
    }

    f32x4 acc[2][4];
    #pragma unroll
    for (int i = 0; i < 2; ++i)
        #pragma unroll
        for (int j = 0; j < 4; ++j) acc[i][j] = (f32x4)(0.f);

    for (int kt = 0; kt < nt; ++kt) {
        float4 v0 = make_float4(0.f, 0.f, 0.f, 0.f);
        float4 v1 = make_float4(0.f, 0.f, 0.f, 0.f);
        if (avalid) {
            const float* p = aptr + kt * GBK;
            v0 = *(const float4*)p;
            v1 = *(const float4*)(p + 4);
        }
        uint4 hi, lo;
        cvt_split_pk(v0, v1, hi, lo);
        __syncthreads();
        *(uint4*)&Ahi[ag8] = hi;
        *(uint4*)&Alo[ag8] = lo;
        #pragma unroll
        for (int i = 0; i < 4; ++i) {
            const int c = w * 4 + i;
            const int plane = c >> 3;
            const int co = (c & 7) * 512;
            const unsigned short* gs =
                (plane ? Btlo : Bthi) + (size_t)kt * 4096 + co + lane * 8;
            __builtin_amdgcn_global_load_lds(
                (const __attribute__((address_space(1))) unsigned int*)gs,
                (__attribute__((address_space(3))) unsigned int*)&Bs[plane][co],
                16, 0, 0);
        }
        __syncthreads();

        bf16x8 ahi[2], alo[2];
        #pragma unroll
        for (int mi = 0; mi < 2; ++mi) {
            ahi[mi] = *(const bf16x8*)&Ahi[aoff[mi]];
            alo[mi] = *(const bf16x8*)&Alo[aoff[mi]];
        }
        #pragma unroll
        for (int ni = 0; ni < 4; ++ni) {
            const bf16x8 bhi = *(const bf16x8*)&Bs[0][boff[ni]];
            const bf16x8 blo = *(const bf16x8*)&Bs[1][boff[ni]];
            #pragma unroll
            for (int mi = 0; mi < 2; ++mi) {
                acc[mi][ni] = __builtin_amdgcn_mfma_f32_16x16x32_bf16(ahi[mi], bhi, acc[mi][ni], 0, 0, 0);
                acc[mi][ni] = __builtin_amdgcn_mfma_f32_16x16x32_bf16(ahi[mi], blo, acc[mi][ni], 0, 0, 0);
                acc[mi][ni] = __builtin_amdgcn_mfma_f32_16x16x32_bf16(alo[mi], bhi, acc[mi][ni], 0, 0, 0);
            }
        }
    }

    // ---- epilogue: z16 store + per-head score dots ----
    const int NH = (H == 4) ? 2 : 1;
    float asc[4], adc[4];
    #pragma unroll
    for (int ni = 0; ni < 4; ++ni) {
        const int col = wc * 64 + ni * 16 + lrow;
        if (H == 4) {
            const int hh = col >> 5, d = col & 31;
            asc[ni] = av[hh * 64 + d];
            adc[ni] = av[hh * 64 + 32 + d];
        } else {
            asc[ni] = av[col];
            adc[ni] = av[128 + col];
        }
    }
    float es[2][4][2], ed[2][4][2];
    #pragma unroll
    for (int mi = 0; mi < 2; ++mi)
        #pragma unroll
        for (int j = 0; j < 4; ++j)
            #pragma unroll
            for (int q = 0; q < 2; ++q) { es[mi][j][q] = 0.f; ed[mi][j][q] = 0.f; }

    #pragma unroll
    for (int mi = 0; mi < 2; ++mi) {
        #pragma unroll
        for (int ni = 0; ni < 4; ++ni) {
            const int hh = (H == 4) ? (ni >> 1) : 0;
            const f32x4 a = acc[mi][ni];
            #pragma unroll
            for (int j = 0; j < 4; ++j) {
                es[mi][j][hh] = fmaf(a[j], asc[ni], es[mi][j][hh]);
                ed[mi][j][hh] = fmaf(a[j], adc[ni], ed[mi][j][hh]);
            }
        }
    }
    #pragma unroll
    for (int mi = 0; mi < 2; ++mi) {
        const int rbase = m0 + wr * 32 + mi * 16 + kg * 4;
        #pragma unroll
        for (int ni = 0; ni < 4; ++ni) {
            const int col = wc * 64 + ni * 16 + lrow;
            const f32x4 a = acc[mi][ni];
            #pragma unroll
            for (int j = 0; j < 4; ++j) {
                const int r = rbase + j;
                if (r < NN) Z16[(size_t)r * CH + col] = bf16_rne(a[j]);
            }
        }
    }
    #pragma unroll
    for (int off = 1; off < 16; off <<= 1) {
        #pragma unroll
        for (int mi = 0; mi < 2; ++mi)
            #pragma unroll
            for (int j = 0; j < 4; ++j)
                #pragma unroll
                for (int q = 0; q < NH; ++q) {
                    es[mi][j][q] += __shfl_xor(es[mi][j][q], off, 64);
                    ed[mi][j][q] += __shfl_xor(ed[mi][j][q], off, 64);
                }
    }
    if (H == 4) {
        if (lrow == 0) {
            #pragma unroll
            for (int mi = 0; mi < 2; ++mi)
                #pragma unroll
                for (int j = 0; j < 4; ++j) {
                    const int r = m0 + wr * 32 + mi * 16 + kg * 4 + j;
                    if (r < NN) {
                        #pragma unroll
                        for (int q = 0; q < 2; ++q) {
                            ss[r * 4 + wc * 2 + q] = es[mi][j][q];
                            sd[r * 4 + wc * 2 + q] = ed[mi][j][q];
                        }
                    }
                }
        }
    } else {
        if (lrow == 0) {
            #pragma unroll
            for (int mi = 0; mi < 2; ++mi)
                #pragma unroll
                for (int j = 0; j < 4; ++j) {
                    const int rl = wr * 32 + mi * 16 + kg * 4 + j;
                    sred[0][rl][wc] = es[mi][j][0];
                    sred[1][rl][wc] = ed[mi][j][0];
                }
        }
        __syncthreads();
        if (t < 64) {
            const int r = m0 + t;
            if (r < NN) {
                ss[r] = sred[0][t][0] + sred[0][t][1];
                sd[r] = sred[1][t][0] + sred[1][t][1];
            }
        }
    }
}

// ---------------- CSR build ----------------
__global__ __launch_bounds__(256) void zero_cc(int* __restrict__ counts, int* __restrict__ cursor)
{
    int i = blockIdx.x * 256 + threadIdx.x;
    if (i < NN) { counts[i] = 0; cursor[i] = 0; }
}

__global__ void count_k(const int* __restrict__ dst, int* __restrict__ counts)
{
    int e = blockIdx.x * blockDim.x + threadIdx.x;
    if (e < NE) atomicAdd(&counts[dst[e]], 1);
}

__global__ __launch_bounds__(256) void scan1(const int* __restrict__ counts,
                                             int* __restrict__ exc, int* __restrict__ bsum)
{
    __shared__ int s[256];
    const int t = threadIdx.x;
    const int i = blockIdx.x * 256 + t;
    const int val = (i < NN) ? counts[i] : 0;
    s[t] = val;
    __syncthreads();
    #pragma unroll
    for (int off = 1; off < 256; off <<= 1) {
        int v = (t >= off) ? s[t - off] : 0;
        __syncthreads();
        s[t] += v;
        __syncthreads();
    }
    if (i < NN) exc[i] = s[t] - val;
    if (t == 255) bsum[blockIdx.x] = s[255];
}

__global__ __launch_bounds__(256) void scan2(const int* __restrict__ bsum,
                                             int* __restrict__ bexc)
{
    __shared__ int s[256];
    const int t = threadIdx.x;
    const int val = (t < NBLK) ? bsum[t] : 0;
    s[t] = val;
    __syncthreads();
    #pragma unroll
    for (int off = 1; off < 256; off <<= 1) {
        int v = (t >= off) ? s[t - off] : 0;
        __syncthreads();
        s[t] += v;
        __syncthreads();
    }
    bexc[t] = s[t] - val;
}

__global__ __launch_bounds__(256) void scan3(const int* __restrict__ exc,
                                             const int* __restrict__ bexc,
                                             int* __restrict__ offsets)
{
    const int i = blockIdx.x * 256 + threadIdx.x;
    if (i < NN) offsets[i] = exc[i] + bexc[i >> 8];
    if (i == 0) offsets[NN] = NE;
}

__global__ void scatter_es(const int* __restrict__ src, const int* __restrict__ dst,
                           const int* __restrict__ offsets, int* __restrict__ cursor,
                           int* __restrict__ es)
{
    int e = blockIdx.x * blockDim.x + threadIdx.x;
    if (e >= NE) return;
    int d = dst[e];
    int p = offsets[d] + atomicAdd(&cursor[d], 1);
    es[p] = src[e];
}

// ---------------- fused softmax + aggregation: one WAVE per dst node, ZERO barriers ----------------
template<int H, bool ELU>
__global__ __launch_bounds__(256) void fused_agg(
    const int* __restrict__ offsets, const int* __restrict__ es,
    const float* __restrict__ s_src, const float* __restrict__ s_dst,
    const unsigned short* __restrict__ z16, float* __restrict__ out)
{
    const int wid = threadIdx.x >> 6;
    const int lane = threadIdx.x & 63;
    const int n = blockIdx.x * 4 + wid;     // NN % 4 == 0
    const int beg = offsets[n], end = offsets[n + 1];
    const int deg = end - beg;

    __shared__ float alpha_sh[4][128][H];
    __shared__ int   es_sh[4][128];

    float sdv[H];
    #pragma unroll
    for (int h = 0; h < H; ++h) sdv[h] = s_dst[(size_t)n * H + h];

    const int myh = (H == 4) ? (lane >> 4) : 0;
    float m[H], ssum[H], inv[H];
    #pragma unroll
    for (int h = 0; h < H; ++h) { m[h] = -INFINITY; ssum[h] = 0.f; }
    float2 acc = make_float2(0.f, 0.f);

    if (deg <= 128) {
        for (int idx = lane; idx < deg; idx += 64) {
            const int s = es[beg + idx];
            es_sh[wid][idx] = s;
            if (H == 4) {
                const float4 sv = *(const float4*)&s_src[(size_t)s * 4];
                const float svv[4] = {sv.x, sv.y, sv.z, sv.w};
                float v4[4];
                #pragma unroll
                for (int h = 0; h < 4; ++h) {
                    float v = svv[h] + sdv[h];
                    v = v > 0.f ? v : 0.01f * v;
                    v4[h] = v;
                    const float mn = fmaxf(m[h], v);
                    ssum[h] = ssum[h] * __expf(m[h] - mn) + __expf(v - mn);
                    m[h] = mn;
                }
                *(float4*)&alpha_sh[wid][idx][0] = make_float4(v4[0], v4[1], v4[2], v4[3]);
            } else {
                float v = s_src[s] + sdv[0];
                v = v > 0.f ? v : 0.01f * v;
                alpha_sh[wid][idx][0] = v;
                const float mn = fmaxf(m[0], v);
                ssum[0] = ssum[0] * __expf(m[0] - mn) + __expf(v - mn);
                m[0] = mn;
            }
        }
        #pragma unroll
        for (int h = 0; h < H; ++h) {
            float mg = m[h];
            #pragma unroll
            for (int off = 1; off < 64; off <<= 1)
                mg = fmaxf(mg, __shfl_xor(mg, off, 64));
            float sg = ssum[h] * __expf(m[h] - mg);
            #pragma unroll
            for (int off = 1; off < 64; off <<= 1)
                sg += __shfl_xor(sg, off, 64);
            m[h] = mg;
            inv[h] = 1.0f / fmaxf(sg, 1e-9f);
        }
        for (int idx = lane; idx < deg; idx += 64) {
            #pragma unroll
            for (int h = 0; h < H; ++h)
                alpha_sh[wid][idx][h] = __expf(alpha_sh[wid][idx][h] - m[h]) * inv[h];
        }
        int j = 0;
        for (; j + 4 <= deg; j += 4) {
            const int s0 = es_sh[wid][j],     s1 = es_sh[wid][j + 1];
            const int s2 = es_sh[wid][j + 2], s3 = es_sh[wid][j + 3];
            const float a0 = alpha_sh[wid][j][myh],     a1 = alpha_sh[wid][j + 1][myh];
            const float a2 = alpha_sh[wid][j + 2][myh], a3 = alpha_sh[wid][j + 3][myh];
            const ushort2 u0 = *(const ushort2*)&z16[(size_t)s0 * CH + lane * 2];
            const ushort2 u1 = *(const ushort2*)&z16[(size_t)s1 * CH + lane * 2];
            const ushort2 u2 = *(const ushort2*)&z16[(size_t)s2 * CH + lane * 2];
            const ushort2 u3 = *(const ushort2*)&z16[(size_t)s3 * CH + lane * 2];
            acc.x = fmaf(a0, bf16_to_f(u0.x), acc.x); acc.y = fmaf(a0, bf16_to_f(u0.y), acc.y);
            acc.x = fmaf(a1, bf16_to_f(u1.x), acc.x); acc.y = fmaf(a1, bf16_to_f(u1.y), acc.y);
            acc.x = fmaf(a2, bf16_to_f(u2.x), acc.x); acc.y = fmaf(a2, bf16_to_f(u2.y), acc.y);
            acc.x = fmaf(a3, bf16_to_f(u3.x), acc.x); acc.y = fmaf(a3, bf16_to_f(u3.y), acc.y);
        }
        for (; j < deg; ++j) {
            const int s0 = es_sh[wid][j];
            const float a0 = alpha_sh[wid][j][myh];
            const ushort2 u0 = *(const ushort2*)&z16[(size_t)s0 * CH + lane * 2];
            acc.x = fmaf(a0, bf16_to_f(u0.x), acc.x); acc.y = fmaf(a0, bf16_to_f(u0.y), acc.y);
        }
    } else {
        for (int i = beg + lane; i < end; i += 64) {
            const int s = es[i];
            if (H == 4) {
                const float4 sv = *(const float4*)&s_src[(size_t)s * 4];
                const float svv[4] = {sv.x, sv.y, sv.z, sv.w};
                #pragma unroll
                for (int h = 0; h < 4; ++h) {
                    float v = svv[h] + sdv[h];
                    v = v > 0.f ? v : 0.01f * v;
                    const float mn = fmaxf(m[h], v);
                    ssum[h] = ssum[h] * __expf(m[h] - mn) + __expf(v - mn);
                    m[h] = mn;
                }
            } else {
                float v = s_src[s] + sdv[0];
                v = v > 0.f ? v : 0.01f * v;
                const float mn = fmaxf(m[0], v);
                ssum[0] = ssum[0] * __expf(m[0] - mn) + __expf(v - mn);
                m[0] = mn;
            }
        }
        #pragma unroll
        for (int h = 0; h < H; ++h) {
            float mg = m[h];
            #pragma unroll
            for (int off = 1; off < 64; off <<= 1)
                mg = fmaxf(mg, __shfl_xor(mg, off, 64));
            float sg = ssum[h] * __expf(m[h] - mg);
            #pragma unroll
            for (int off = 1; off < 64; off <<= 1)
                sg += __shfl_xor(sg, off, 64);
            m[h] = mg;
            inv[h] = 1.0f / fmaxf(sg, 1e-9f);
        }
        const int nch = (deg + 127) >> 7;
        for (int k = 0; k < nch; ++k) {
            const int base = beg + k * 128;
            int cnt = end - base;
            cnt = cnt < 0 ? 0 : (cnt > 128 ? 128 : cnt);
            for (int idx = lane; idx < cnt; idx += 64) {
                const int s = es[base + idx];
                es_sh[wid][idx] = s;
                if (H == 4) {
                    const float4 sv = *(const float4*)&s_src[(size_t)s * 4];
                    const float svv[4] = {sv.x, sv.y, sv.z, sv.w};
                    float a4[4];
                    #pragma unroll
                    for (int h = 0; h < 4; ++h) {
                        float v = svv[h] + sdv[h];
                        v = v > 0.f ? v : 0.01f * v;
                        a4[h] = __expf(v - m[h]) * inv[h];
                    }
                    *(float4*)&alpha_sh[wid][idx][0] = make_float4(a4[0], a4[1], a4[2], a4[3]);
                } else {
                    float v = s_src[s] + sdv[0];
                    v = v > 0.f ? v : 0.01f * v;
                    alpha_sh[wid][idx][0] = __expf(v - m[0]) * inv[0];
                }
            }
            for (int j = 0; j < cnt; ++j) {
                const int s0 = es_sh[wid][j];
                const float a0 = alpha_sh[wid][j][myh];
                const ushort2 u0 = *(const ushort2*)&z16[(size_t)s0 * CH + lane * 2];
                acc.x = fmaf(a0, bf16_to_f(u0.x), acc.x);
                acc.y = fmaf(a0, bf16_to_f(u0.y), acc.y);
            }
        }
    }

    if (ELU) {
        acc.x = acc.x > 0.f ? acc.x : expm1f(acc.x);
        acc.y = acc.y > 0.f ? acc.y : expm1f(acc.y);
    }
    *(float2*)&out[(size_t)n * CH + lane * 2] = acc;
}

// ---------------- host ----------------
extern "C" void kernel_launch(void* const* d_in, const int* in_sizes, int n_in,
                              void* d_out, int out_size, void* d_ws, size_t ws_size,
                              hipStream_t stream)
{
    const float* h   = (const float*)d_in[0];
    const float* W1  = (const float*)d_in[1];
    const float* a1  = (const float*)d_in[2];
    const float* W2  = (const float*)d_in[3];
    const float* a2  = (const float*)d_in[4];
    const int*   src = (const int*)d_in[5];
    const int*   dst = (const int*)d_in[6];
    float* out = (float*)d_out;

    char* ws = (char*)d_ws;
    unsigned short* Bthi1 = (unsigned short*)(ws + 0);          // 192KB
    unsigned short* Btlo1 = (unsigned short*)(ws + 196608);     // 192KB
    unsigned short* Bthi2 = (unsigned short*)(ws + 393216);     // 32KB
    unsigned short* Btlo2 = (unsigned short*)(ws + 425984);     // 32KB
    float* ss      = (float*)(ws + 458752);                     // 800KB
    float* sd      = (float*)(ws + 1258752);                    // 800KB
    int*   counts  = (int*)  (ws + 2058752);                    // 200KB
    int*   exc     = (int*)  (ws + 2258752);                    // 200KB
    int*   bsum    = (int*)  (ws + 2458752);                    // 1KB
    int*   bexc    = (int*)  (ws + 2459776);                    // 1KB
    int*   offsets = (int*)  (ws + 2460800);                    // 200KB+4
    int*   cursor  = (int*)  (ws + 2661056);                    // 200KB
    int*   es      = (int*)  (ws + 2861056);                    // 3.2MB
    unsigned short* z16 = (unsigned short*)(ws + 6061056);      // 12.8MB
    float* h1      = (float*)(ws + 18861056);                   // 25.6MB

    const int EB = 256;
    const int egrid = (NE + EB - 1) / EB;
    const int sgrid = NN / 4;

    // --- CSR build (shared by both layers) ---
    zero_cc<<<NBLK, 256, 0, stream>>>(counts, cursor);
    count_k<<<egrid, EB, 0, stream>>>(dst, counts);
    scan1<<<NBLK, 256, 0, stream>>>(counts, exc, bsum);
    scan2<<<1, 256, 0, stream>>>(bsum, bexc);
    scan3<<<NBLK, 256, 0, stream>>>(exc, bexc, offsets);
    scatter_es<<<egrid, EB, 0, stream>>>(src, dst, offsets, cursor, es);

    // --- weight prep (split bf16, tiled+swizzled) ---
    prep_b1<<<(CH * IND + 255) / 256, 256, 0, stream>>>(W1, Bthi1, Btlo1);
    prep_b2<<<(CH * CH + 255) / 256, 256, 0, stream>>>(W2, Bthi2, Btlo2);

    // --- layer 1: GEMM (fused z16 + scores) -> aggregate ---
    gemm_fused<4><<<MBLKS, 256, 0, stream>>>(h, Bthi1, Btlo1, a1, z16, ss, sd, IND);
    fused_agg<4, true><<<sgrid, 256, 0, stream>>>(offsets, es, ss, sd, z16, h1);

    // --- layer 2: GEMM (fused z16 + scores) -> aggregate ---
    gemm_fused<1><<<MBLKS, 256, 0, stream>>>(h1, Bthi2, Btlo2, a2, z16, ss, sd, CH);
    fused_agg<1, false><<<sgrid, 256, 0, stream>>>(offsets, es, ss, sd, z16, out);
}

// Round 17
// 235.079 us; speedup vs baseline: 1.0643x; 1.0228x over previous
//
#include <hip/hip_runtime.h>

#define NN 50000
#define NE 800000
#define IND 768
#define CH  128    // output channels per node for both layers
#define NBLK 196   // ceil(NN/256)
#define GBM 64
#define GBK 32
#define MBLKS 782  // ceil(NN/GBM)

typedef __attribute__((ext_vector_type(8))) short bf16x8;
typedef __attribute__((ext_vector_type(4))) float f32x4;

// ---------------- bf16 split helpers ----------------
__device__ __forceinline__ unsigned short bf16_rne(float f) {
    unsigned u = __float_as_uint(f);
    u += 0x7fffu + ((u >> 16) & 1u);
    return (unsigned short)(u >> 16);
}
__device__ __forceinline__ float bf16_to_f(unsigned short b) {
    return __uint_as_float(((unsigned)b) << 16);
}

// fast split via packed cvt: hi = cvt_pk(v), lo = cvt_pk(v - hi)
__device__ __forceinline__ void cvt_split_pk(const float4& u0, const float4& u1,
                                             uint4& hi, uint4& lo)
{
    unsigned h0, h1, h2, h3;
    asm("v_cvt_pk_bf16_f32 %0, %1, %2" : "=v"(h0) : "v"(u0.x), "v"(u0.y));
    asm("v_cvt_pk_bf16_f32 %0, %1, %2" : "=v"(h1) : "v"(u0.z), "v"(u0.w));
    asm("v_cvt_pk_bf16_f32 %0, %1, %2" : "=v"(h2) : "v"(u1.x), "v"(u1.y));
    asm("v_cvt_pk_bf16_f32 %0, %1, %2" : "=v"(h3) : "v"(u1.z), "v"(u1.w));
    const float l0 = u0.x - __uint_as_float(h0 << 16);
    const float l1 = u0.y - __uint_as_float(h0 & 0xffff0000u);
    const float l2 = u0.z - __uint_as_float(h1 << 16);
    const float l3 = u0.w - __uint_as_float(h1 & 0xffff0000u);
    const float l4 = u1.x - __uint_as_float(h2 << 16);
    const float l5 = u1.y - __uint_as_float(h2 & 0xffff0000u);
    const float l6 = u1.z - __uint_as_float(h3 << 16);
    const float l7 = u1.w - __uint_as_float(h3 & 0xffff0000u);
    unsigned g0, g1, g2, g3;
    asm("v_cvt_pk_bf16_f32 %0, %1, %2" : "=v"(g0) : "v"(l0), "v"(l1));
    asm("v_cvt_pk_bf16_f32 %0, %1, %2" : "=v"(g1) : "v"(l2), "v"(l3));
    asm("v_cvt_pk_bf16_f32 %0, %1, %2" : "=v"(g2) : "v"(l4), "v"(l5));
    asm("v_cvt_pk_bf16_f32 %0, %1, %2" : "=v"(g3) : "v"(l6), "v"(l7));
    hi = make_uint4(h0, h1, h2, h3);
    lo = make_uint4(g0, g1, g2, g3);
}

// ---------------- prep: W -> K-tiled, 8-way-swizzled bf16 hi/lo planes ----------------
__global__ void prep_b1(const float* __restrict__ W1,
                        unsigned short* __restrict__ Bhi, unsigned short* __restrict__ Blo)
{
    int idx = blockIdx.x * blockDim.x + threadIdx.x;   // n*IND + k
    if (idx >= CH * IND) return;
    int n = idx / IND, k = idx % IND;
    float v = W1[(size_t)(n >> 5) * IND * 32 + (size_t)k * 32 + (n & 31)];
    int kt = k >> 5, kk = k & 31, j = kk >> 3, e = kk & 7;
    int g = n * 4 + (j ^ ((n >> 1) & 3));
    int off = kt * 4096 + g * 8 + e;
    unsigned short hi = bf16_rne(v);
    float lo = v - bf16_to_f(hi);
    Bhi[off] = hi;
    Blo[off] = bf16_rne(lo);
}

__global__ void prep_b2(const float* __restrict__ W2,
                        unsigned short* __restrict__ Bhi, unsigned short* __restrict__ Blo)
{
    int idx = blockIdx.x * blockDim.x + threadIdx.x;   // n*CH + k
    if (idx >= CH * CH) return;
    int n = idx / CH, k = idx % CH;
    float v = W2[(size_t)k * CH + n];
    int kt = k >> 5, kk = k & 31, j = kk >> 3, e = kk & 7;
    int g = n * 4 + (j ^ ((n >> 1) & 3));
    int off = kt * 4096 + g * 8 + e;
    unsigned short hi = bf16_rne(v);
    float lo = v - bf16_to_f(hi);
    Bhi[off] = hi;
    Blo[off] = bf16_rne(lo);
}

// ---------------- GEMM with fused epilogue: z16 + s_src/s_dst (round-14 schedule) ----------------
template<int H>
__global__ __launch_bounds__(256) void gemm_fused(
    const float* __restrict__ A,
    const unsigned short* __restrict__ Bthi, const unsigned short* __restrict__ Btlo,
    const float* __restrict__ av,            // attention vec: [H][2*(128/H)]
    unsigned short* __restrict__ Z16,
    float* __restrict__ ss, float* __restrict__ sd, int K)
{
    __shared__ unsigned short Ahi[2048];
    __shared__ unsigned short Alo[2048];
    __shared__ unsigned short Bs[2][4096];
    __shared__ float sred[2][64][2];         // H==1 cross-wave reduce

    const int t = threadIdx.x;
    const int lane = t & 63;
    const int w = t >> 6;
    const int wr = w >> 1, wc = w & 1;
    const int lrow = lane & 15, kg = lane >> 4;
    const int m0 = blockIdx.x * GBM;
    const int nt = K >> 5;

    const int ar = t >> 2, aj = t & 3;
    const bool avalid = (m0 + ar) < NN;
    const float* aptr = A + (size_t)(avalid ? (m0 + ar) : 0) * K + aj * 8;
    const int ag8 = (ar * 4 + (aj ^ ((ar >> 1) & 3))) * 8;

    int aoff[2];
    #pragma unroll
    for (int mi = 0; mi < 2; ++mi) {
        const int r = wr * 32 + mi * 16 + lrow;
        aoff[mi] = (r * 4 + (kg ^ ((r >> 1) & 3))) * 8;
    }
    int boff[4];
    #pragma unroll
    for (int ni = 0; ni < 4; ++ni) {
        const int n = wc * 64 + ni * 16 + lrow;
        boff[ni] = (n * 4 + (kg ^ ((n >> 1) & 3))) * 8;
    }

    f32x4 acc[2][4];
    #pragma unroll
    for (int i = 0; i < 2; ++i)
        #pragma unroll
        for (int j = 0; j < 4; ++j) acc[i][j] = (f32x4)(0.f);

    for (int kt = 0; kt < nt; ++kt) {
        float4 v0 = make_float4(0.f, 0.f, 0.f, 0.f);
        float4 v1 = make_float4(0.f, 0.f, 0.f, 0.f);
        if (avalid) {
            const float* p = aptr + kt * GBK;
            v0 = *(const float4*)p;
            v1 = *(const float4*)(p + 4);
        }
        uint4 hi, lo;
        cvt_split_pk(v0, v1, hi, lo);
        __syncthreads();
        *(uint4*)&Ahi[ag8] = hi;
        *(uint4*)&Alo[ag8] = lo;
        #pragma unroll
        for (int i = 0; i < 4; ++i) {
            const int c = w * 4 + i;
            const int plane = c >> 3;
            const int co = (c & 7) * 512;
            const unsigned short* gs =
                (plane ? Btlo : Bthi) + (size_t)kt * 4096 + co + lane * 8;
            __builtin_amdgcn_global_load_lds(
                (const __attribute__((address_space(1))) unsigned int*)gs,
                (__attribute__((address_space(3))) unsigned int*)&Bs[plane][co],
                16, 0, 0);
        }
        __syncthreads();

        bf16x8 ahi[2], alo[2];
        #pragma unroll
        for (int mi = 0; mi < 2; ++mi) {
            ahi[mi] = *(const bf16x8*)&Ahi[aoff[mi]];
            alo[mi] = *(const bf16x8*)&Alo[aoff[mi]];
        }
        #pragma unroll
        for (int ni = 0; ni < 4; ++ni) {
            const bf16x8 bhi = *(const bf16x8*)&Bs[0][boff[ni]];
            const bf16x8 blo = *(const bf16x8*)&Bs[1][boff[ni]];
            #pragma unroll
            for (int mi = 0; mi < 2; ++mi) {
                acc[mi][ni] = __builtin_amdgcn_mfma_f32_16x16x32_bf16(ahi[mi], bhi, acc[mi][ni], 0, 0, 0);
                acc[mi][ni] = __builtin_amdgcn_mfma_f32_16x16x32_bf16(ahi[mi], blo, acc[mi][ni], 0, 0, 0);
                acc[mi][ni] = __builtin_amdgcn_mfma_f32_16x16x32_bf16(alo[mi], bhi, acc[mi][ni], 0, 0, 0);
            }
        }
    }

    // ---- epilogue: z16 store + per-head score dots ----
    const int NH = (H == 4) ? 2 : 1;
    float asc[4], adc[4];
    #pragma unroll
    for (int ni = 0; ni < 4; ++ni) {
        const int col = wc * 64 + ni * 16 + lrow;
        if (H == 4) {
            const int hh = col >> 5, d = col & 31;
            asc[ni] = av[hh * 64 + d];
            adc[ni] = av[hh * 64 + 32 + d];
        } else {
            asc[ni] = av[col];
            adc[ni] = av[128 + col];
        }
    }
    float es[2][4][2], ed[2][4][2];
    #pragma unroll
    for (int mi = 0; mi < 2; ++mi)
        #pragma unroll
        for (int j = 0; j < 4; ++j)
            #pragma unroll
            for (int q = 0; q < 2; ++q) { es[mi][j][q] = 0.f; ed[mi][j][q] = 0.f; }

    #pragma unroll
    for (int mi = 0; mi < 2; ++mi) {
        #pragma unroll
        for (int ni = 0; ni < 4; ++ni) {
            const int hh = (H == 4) ? (ni >> 1) : 0;
            const f32x4 a = acc[mi][ni];
            #pragma unroll
            for (int j = 0; j < 4; ++j) {
                es[mi][j][hh] = fmaf(a[j], asc[ni], es[mi][j][hh]);
                ed[mi][j][hh] = fmaf(a[j], adc[ni], ed[mi][j][hh]);
            }
        }
    }
    #pragma unroll
    for (int mi = 0; mi < 2; ++mi) {
        const int rbase = m0 + wr * 32 + mi * 16 + kg * 4;
        #pragma unroll
        for (int ni = 0; ni < 4; ++ni) {
            const int col = wc * 64 + ni * 16 + lrow;
            const f32x4 a = acc[mi][ni];
            #pragma unroll
            for (int j = 0; j < 4; ++j) {
                const int r = rbase + j;
                if (r < NN) Z16[(size_t)r * CH + col] = bf16_rne(a[j]);
            }
        }
    }
    #pragma unroll
    for (int off = 1; off < 16; off <<= 1) {
        #pragma unroll
        for (int mi = 0; mi < 2; ++mi)
            #pragma unroll
            for (int j = 0; j < 4; ++j)
                #pragma unroll
                for (int q = 0; q < NH; ++q) {
                    es[mi][j][q] += __shfl_xor(es[mi][j][q], off, 64);
                    ed[mi][j][q] += __shfl_xor(ed[mi][j][q], off, 64);
                }
    }
    if (H == 4) {
        if (lrow == 0) {
            #pragma unroll
            for (int mi = 0; mi < 2; ++mi)
                #pragma unroll
                for (int j = 0; j < 4; ++j) {
                    const int r = m0 + wr * 32 + mi * 16 + kg * 4 + j;
                    if (r < NN) {
                        #pragma unroll
                        for (int q = 0; q < 2; ++q) {
                            ss[r * 4 + wc * 2 + q] = es[mi][j][q];
                            sd[r * 4 + wc * 2 + q] = ed[mi][j][q];
                        }
                    }
                }
        }
    } else {
        if (lrow == 0) {
            #pragma unroll
            for (int mi = 0; mi < 2; ++mi)
                #pragma unroll
                for (int j = 0; j < 4; ++j) {
                    const int rl = wr * 32 + mi * 16 + kg * 4 + j;
                    sred[0][rl][wc] = es[mi][j][0];
                    sred[1][rl][wc] = ed[mi][j][0];
                }
        }
        __syncthreads();
        if (t < 64) {
            const int r = m0 + t;
            if (r < NN) {
                ss[r] = sred[0][t][0] + sred[0][t][1];
                sd[r] = sred[1][t][0] + sred[1][t][1];
            }
        }
    }
}

// ---------------- CSR build ----------------
__global__ __launch_bounds__(256) void zero_cc(int* __restrict__ counts, int* __restrict__ cursor)
{
    int i = blockIdx.x * 256 + threadIdx.x;
    if (i < NN) { counts[i] = 0; cursor[i] = 0; }
}

__global__ void count_k(const int* __restrict__ dst, int* __restrict__ counts)
{
    int e = blockIdx.x * blockDim.x + threadIdx.x;
    if (e < NE) atomicAdd(&counts[dst[e]], 1);
}

__global__ __launch_bounds__(256) void scan1(const int* __restrict__ counts,
                                             int* __restrict__ exc, int* __restrict__ bsum)
{
    __shared__ int s[256];
    const int t = threadIdx.x;
    const int i = blockIdx.x * 256 + t;
    const int val = (i < NN) ? counts[i] : 0;
    s[t] = val;
    __syncthreads();
    #pragma unroll
    for (int off = 1; off < 256; off <<= 1) {
        int v = (t >= off) ? s[t - off] : 0;
        __syncthreads();
        s[t] += v;
        __syncthreads();
    }
    if (i < NN) exc[i] = s[t] - val;
    if (t == 255) bsum[blockIdx.x] = s[255];
}

__global__ __launch_bounds__(256) void scan2(const int* __restrict__ bsum,
                                             int* __restrict__ bexc)
{
    __shared__ int s[256];
    const int t = threadIdx.x;
    const int val = (t < NBLK) ? bsum[t] : 0;
    s[t] = val;
    __syncthreads();
    #pragma unroll
    for (int off = 1; off < 256; off <<= 1) {
        int v = (t >= off) ? s[t - off] : 0;
        __syncthreads();
        s[t] += v;
        __syncthreads();
    }
    bexc[t] = s[t] - val;
}

__global__ __launch_bounds__(256) void scan3(const int* __restrict__ exc,
                                             const int* __restrict__ bexc,
                                             int* __restrict__ offsets)
{
    const int i = blockIdx.x * 256 + threadIdx.x;
    if (i < NN) offsets[i] = exc[i] + bexc[i >> 8];
    if (i == 0) offsets[NN] = NE;
}

__global__ void scatter_es(const int* __restrict__ src, const int* __restrict__ dst,
                           const int* __restrict__ offsets, int* __restrict__ cursor,
                           int* __restrict__ es)
{
    int e = blockIdx.x * blockDim.x + threadIdx.x;
    if (e >= NE) return;
    int d = dst[e];
    int p = offsets[d] + atomicAdd(&cursor[d], 1);
    es[p] = src[e];
}

// ---------------- fused softmax + aggregation: one HALF-WAVE per dst node ----------------
// Block 256 thr = 4 waves = 8 nodes. Lane hl=lane&31 owns channels hl*4..hl*4+3 (ushort4
// gather, 8B/lane). Shuffle reduces use offsets 1..16 (stay within the 32-lane half).
// All LDS slices are half-wave-private; same-wave ordering -> zero barriers.
template<int H, bool ELU>
__global__ __launch_bounds__(256) void fused_agg(
    const int* __restrict__ offsets, const int* __restrict__ es,
    const float* __restrict__ s_src, const float* __restrict__ s_dst,
    const unsigned short* __restrict__ z16, float* __restrict__ out)
{
    const int lane = threadIdx.x & 63;
    const int hl = lane & 31;               // lane within half
    const int slot = threadIdx.x >> 5;      // 0..7 node slot in block
    const int n = blockIdx.x * 8 + slot;    // NN % 8 == 0
    const int beg = offsets[n], end = offsets[n + 1];
    const int deg = end - beg;

    __shared__ float alpha_sh[8][128][H];
    __shared__ int   es_sh[8][128];

    float sdv[H];
    #pragma unroll
    for (int h = 0; h < H; ++h) sdv[h] = s_dst[(size_t)n * H + h];

    const int c0 = hl * 4;
    const int myh = (H == 4) ? (c0 >> 5) : 0;   // this lane's channel head
    float m[H], ssum[H], inv[H];
    #pragma unroll
    for (int h = 0; h < H; ++h) { m[h] = -INFINITY; ssum[h] = 0.f; }
    float4 acc = make_float4(0.f, 0.f, 0.f, 0.f);

    if (deg <= 128) {
        // ---- pass 1: gather scores once, cache v in half-wave-private LDS ----
        for (int idx = hl; idx < deg; idx += 32) {
            const int s = es[beg + idx];
            es_sh[slot][idx] = s;
            if (H == 4) {
                const float4 sv = *(const float4*)&s_src[(size_t)s * 4];
                const float svv[4] = {sv.x, sv.y, sv.z, sv.w};
                float v4[4];
                #pragma unroll
                for (int h = 0; h < 4; ++h) {
                    float v = svv[h] + sdv[h];
                    v = v > 0.f ? v : 0.01f * v;
                    v4[h] = v;
                    const float mn = fmaxf(m[h], v);
                    ssum[h] = ssum[h] * __expf(m[h] - mn) + __expf(v - mn);
                    m[h] = mn;
                }
                *(float4*)&alpha_sh[slot][idx][0] = make_float4(v4[0], v4[1], v4[2], v4[3]);
            } else {
                float v = s_src[s] + sdv[0];
                v = v > 0.f ? v : 0.01f * v;
                alpha_sh[slot][idx][0] = v;
                const float mn = fmaxf(m[0], v);
                ssum[0] = ssum[0] * __expf(m[0] - mn) + __expf(v - mn);
                m[0] = mn;
            }
        }
        // ---- half-wave reduce: global max, scaled sum (offsets 1..16 stay in half) ----
        #pragma unroll
        for (int h = 0; h < H; ++h) {
            float mg = m[h];
            #pragma unroll
            for (int off = 1; off < 32; off <<= 1)
                mg = fmaxf(mg, __shfl_xor(mg, off, 64));
            float sg = ssum[h] * __expf(m[h] - mg);
            #pragma unroll
            for (int off = 1; off < 32; off <<= 1)
                sg += __shfl_xor(sg, off, 64);
            m[h] = mg;
            inv[h] = 1.0f / fmaxf(sg, 1e-9f);
        }
        // ---- convert cached v -> alpha in place ----
        for (int idx = hl; idx < deg; idx += 32) {
            #pragma unroll
            for (int h = 0; h < H; ++h)
                alpha_sh[slot][idx][h] = __expf(alpha_sh[slot][idx][h] - m[h]) * inv[h];
        }
        // ---- PV gather, 4-unrolled ushort4 (8B/lane) ----
        int j = 0;
        for (; j + 4 <= deg; j += 4) {
            const int s0 = es_sh[slot][j],     s1 = es_sh[slot][j + 1];
            const int s2 = es_sh[slot][j + 2], s3 = es_sh[slot][j + 3];
            const float a0 = alpha_sh[slot][j][myh],     a1 = alpha_sh[slot][j + 1][myh];
            const float a2 = alpha_sh[slot][j + 2][myh], a3 = alpha_sh[slot][j + 3][myh];
            const ushort4 u0 = *(const ushort4*)&z16[(size_t)s0 * CH + c0];
            const ushort4 u1 = *(const ushort4*)&z16[(size_t)s1 * CH + c0];
            const ushort4 u2 = *(const ushort4*)&z16[(size_t)s2 * CH + c0];
            const ushort4 u3 = *(const ushort4*)&z16[(size_t)s3 * CH + c0];
            acc.x = fmaf(a0, bf16_to_f(u0.x), acc.x); acc.y = fmaf(a0, bf16_to_f(u0.y), acc.y);
            acc.z = fmaf(a0, bf16_to_f(u0.z), acc.z); acc.w = fmaf(a0, bf16_to_f(u0.w), acc.w);
            acc.x = fmaf(a1, bf16_to_f(u1.x), acc.x); acc.y = fmaf(a1, bf16_to_f(u1.y), acc.y);
            acc.z = fmaf(a1, bf16_to_f(u1.z), acc.z); acc.w = fmaf(a1, bf16_to_f(u1.w), acc.w);
            acc.x = fmaf(a2, bf16_to_f(u2.x), acc.x); acc.y = fmaf(a2, bf16_to_f(u2.y), acc.y);
            acc.z = fmaf(a2, bf16_to_f(u2.z), acc.z); acc.w = fmaf(a2, bf16_to_f(u2.w), acc.w);
            acc.x = fmaf(a3, bf16_to_f(u3.x), acc.x); acc.y = fmaf(a3, bf16_to_f(u3.y), acc.y);
            acc.z = fmaf(a3, bf16_to_f(u3.z), acc.z); acc.w = fmaf(a3, bf16_to_f(u3.w), acc.w);
        }
        for (; j < deg; ++j) {
            const int s0 = es_sh[slot][j];
            const float a0 = alpha_sh[slot][j][myh];
            const ushort4 u0 = *(const ushort4*)&z16[(size_t)s0 * CH + c0];
            acc.x = fmaf(a0, bf16_to_f(u0.x), acc.x); acc.y = fmaf(a0, bf16_to_f(u0.y), acc.y);
            acc.z = fmaf(a0, bf16_to_f(u0.z), acc.z); acc.w = fmaf(a0, bf16_to_f(u0.w), acc.w);
        }
    } else {
        // ---- fallback: chunked, barrier-free (half-wave-private LDS) ----
        for (int i = beg + hl; i < end; i += 32) {
            const int s = es[i];
            if (H == 4) {
                const float4 sv = *(const float4*)&s_src[(size_t)s * 4];
                const float svv[4] = {sv.x, sv.y, sv.z, sv.w};
                #pragma unroll
                for (int h = 0; h < 4; ++h) {
                    float v = svv[h] + sdv[h];
                    v = v > 0.f ? v : 0.01f * v;
                    const float mn = fmaxf(m[h], v);
                    ssum[h] = ssum[h] * __expf(m[h] - mn) + __expf(v - mn);
                    m[h] = mn;
                }
            } else {
                float v = s_src[s] + sdv[0];
                v = v > 0.f ? v : 0.01f * v;
                const float mn = fmaxf(m[0], v);
                ssum[0] = ssum[0] * __expf(m[0] - mn) + __expf(v - mn);
                m[0] = mn;
            }
        }
        #pragma unroll
        for (int h = 0; h < H; ++h) {
            float mg = m[h];
            #pragma unroll
            for (int off = 1; off < 32; off <<= 1)
                mg = fmaxf(mg, __shfl_xor(mg, off, 64));
            float sg = ssum[h] * __expf(m[h] - mg);
            #pragma unroll
            for (int off = 1; off < 32; off <<= 1)
                sg += __shfl_xor(sg, off, 64);
            m[h] = mg;
            inv[h] = 1.0f / fmaxf(sg, 1e-9f);
        }
        const int nch = (deg + 127) >> 7;
        for (int k = 0; k < nch; ++k) {
            const int base = beg + k * 128;
            int cnt = end - base;
            cnt = cnt < 0 ? 0 : (cnt > 128 ? 128 : cnt);
            for (int idx = hl; idx < cnt; idx += 32) {
                const int s = es[base + idx];
                es_sh[slot][idx] = s;
                if (H == 4) {
                    const float4 sv = *(const float4*)&s_src[(size_t)s * 4];
                    const float svv[4] = {sv.x, sv.y, sv.z, sv.w};
                    float a4[4];
                    #pragma unroll
                    for (int h = 0; h < 4; ++h) {
                        float v = svv[h] + sdv[h];
                        v = v > 0.f ? v : 0.01f * v;
                        a4[h] = __expf(v - m[h]) * inv[h];
                    }
                    *(float4*)&alpha_sh[slot][idx][0] = make_float4(a4[0], a4[1], a4[2], a4[3]);
                } else {
                    float v = s_src[s] + sdv[0];
                    v = v > 0.f ? v : 0.01f * v;
                    alpha_sh[slot][idx][0] = __expf(v - m[0]) * inv[0];
                }
            }
            for (int j = 0; j < cnt; ++j) {
                const int s0 = es_sh[slot][j];
                const float a0 = alpha_sh[slot][j][myh];
                const ushort4 u0 = *(const ushort4*)&z16[(size_t)s0 * CH + c0];
                acc.x = fmaf(a0, bf16_to_f(u0.x), acc.x); acc.y = fmaf(a0, bf16_to_f(u0.y), acc.y);
                acc.z = fmaf(a0, bf16_to_f(u0.z), acc.z); acc.w = fmaf(a0, bf16_to_f(u0.w), acc.w);
            }
        }
    }

    if (ELU) {
        acc.x = acc.x > 0.f ? acc.x : expm1f(acc.x);
        acc.y = acc.y > 0.f ? acc.y : expm1f(acc.y);
        acc.z = acc.z > 0.f ? acc.z : expm1f(acc.z);
        acc.w = acc.w > 0.f ? acc.w : expm1f(acc.w);
    }
    *(float4*)&out[(size_t)n * CH + c0] = acc;
}

// ---------------- host ----------------
extern "C" void kernel_launch(void* const* d_in, const int* in_sizes, int n_in,
                              void* d_out, int out_size, void* d_ws, size_t ws_size,
                              hipStream_t stream)
{
    const float* h   = (const float*)d_in[0];
    const float* W1  = (const float*)d_in[1];
    const float* a1  = (const float*)d_in[2];
    const float* W2  = (const float*)d_in[3];
    const float* a2  = (const float*)d_in[4];
    const int*   src = (const int*)d_in[5];
    const int*   dst = (const int*)d_in[6];
    float* out = (float*)d_out;

    char* ws = (char*)d_ws;
    unsigned short* Bthi1 = (unsigned short*)(ws + 0);          // 192KB
    unsigned short* Btlo1 = (unsigned short*)(ws + 196608);     // 192KB
    unsigned short* Bthi2 = (unsigned short*)(ws + 393216);     // 32KB
    unsigned short* Btlo2 = (unsigned short*)(ws + 425984);     // 32KB
    float* ss      = (float*)(ws + 458752);                     // 800KB
    float* sd      = (float*)(ws + 1258752);                    // 800KB
    int*   counts  = (int*)  (ws + 2058752);                    // 200KB
    int*   exc     = (int*)  (ws + 2258752);                    // 200KB
    int*   bsum    = (int*)  (ws + 2458752);                    // 1KB
    int*   bexc    = (int*)  (ws + 2459776);                    // 1KB
    int*   offsets = (int*)  (ws + 2460800);                    // 200KB+4
    int*   cursor  = (int*)  (ws + 2661056);                    // 200KB
    int*   es      = (int*)  (ws + 2861056);                    // 3.2MB
    unsigned short* z16 = (unsigned short*)(ws + 6061056);      // 12.8MB
    float* h1      = (float*)(ws + 18861056);                   // 25.6MB

    const int EB = 256;
    const int egrid = (NE + EB - 1) / EB;
    const int agrid = NN / 8;   // 6250, one half-wave per node

    // --- CSR build (shared by both layers) ---
    zero_cc<<<NBLK, 256, 0, stream>>>(counts, cursor);
    count_k<<<egrid, EB, 0, stream>>>(dst, counts);
    scan1<<<NBLK, 256, 0, stream>>>(counts, exc, bsum);
    scan2<<<1, 256, 0, stream>>>(bsum, bexc);
    scan3<<<NBLK, 256, 0, stream>>>(exc, bexc, offsets);
    scatter_es<<<egrid, EB, 0, stream>>>(src, dst, offsets, cursor, es);

    // --- weight prep (split bf16, tiled+swizzled) ---
    prep_b1<<<(CH * IND + 255) / 256, 256, 0, stream>>>(W1, Bthi1, Btlo1);
    prep_b2<<<(CH * CH + 255) / 256, 256, 0, stream>>>(W2, Bthi2, Btlo2);

    // --- layer 1: GEMM (fused z16 + scores) -> aggregate ---
    gemm_fused<4><<<MBLKS, 256, 0, stream>>>(h, Bthi1, Btlo1, a1, z16, ss, sd, IND);
    fused_agg<4, true><<<agrid, 256, 0, stream>>>(offsets, es, ss, sd, z16, h1);

    // --- layer 2: GEMM (fused z16 + scores) -> aggregate ---
    gemm_fused<1><<<MBLKS, 256, 0, stream>>>(h1, Bthi2, Btlo2, a2, z16, ss, sd, CH);
    fused_agg<1, false><<<agrid, 256, 0, stream>>>(offsets, es, ss, sd, z16, out);
}